// Round 6
// baseline (4392.117 us; speedup 1.0000x reference)
//
#include <hip/hip_runtime.h>
#include <stdint.h>

// Baum-Welch forward-backward posteriors (log_gamma), MI355X gfx950.
//
// R9 -> R10: fix the rbuf WAR race that broke R9; keep the MFMA recurrence.
//  - R9 bug: rbuf (output-row staging) was written at the TOP of each step,
//    before any barrier -> a fast wave overwrote rows a slow wave was still
//    flushing. Fix: ALL rbuf/xfrag writes live in the post-B1 region; the
//    flush-read (post-B2, step t) and next write (post-B1, step t+1) are
//    separated by B1(t+1). No double-buffer needed.
//  - 16 sequences per block (16 blocks): per step one 256x16x256 GEMM =
//    128 x mfma_f32_16x16x32_f16 per block (16/wave, 8 waves), A=exp(lA)
//    static in registers (fwd: A^T tiles, bwd: A tiles), B = staged
//    256-state x 16-seq fp16 vector batch in LDS, written directly in
//    fragment layout (A and B share the (lane,elem)->k map, so any HW
//    k-permutation cancels).
//  - fp32 accumulate; per-SEQUENCE exact-max rescale per step (smax LDS
//    exchange; 2 lgkm-only barriers/step). alpha / gamma numerators stored
//    fp32; only the recurrence operands are fp16.
//  - MFMA dep chain split 8 -> 4+4 (two accumulators per tile, then add).
//  - Flush: one t-row (16 seq x 256 states) per step, wave w handles seqs
//    w and w+8, lane reads rbuf[seq][4l..4l+3] (canonical contiguous b128).
//  - gamma_norm streaming pass unchanged.

#define NB 256
#define TT 512
#define KK 256
#define VV 4096
#define SPB 16            // sequences per block
#define NBLK (NB / SPB)   // 16 blocks
#define LOG2E 1.44269504088896f
#define LN2 0.693147180559945f

typedef float f4 __attribute__((ext_vector_type(4)));
typedef _Float16 h8 __attribute__((ext_vector_type(8)));
typedef _Float16 h4 __attribute__((ext_vector_type(4)));

__device__ __forceinline__ void bar_lds() {
  // Workgroup barrier draining LDS only (global loads/stores stay in flight).
  asm volatile("s_waitcnt lgkmcnt(0)" ::: "memory");
  __builtin_amdgcn_s_barrier();
}

// MODE 0: forward (writes scaled fp32 alpha rows 0..511).
// MODE 1: backward (overwrites rows 510..0 with alpha*beta; row 511 stays
//         alpha_511 = gamma numerator since beta_511 = 1).
template <int MODE>
__global__ __launch_bounds__(512, 1) void hmm_mfma(
    const float* __restrict__ lpi, const float* __restrict__ lA,
    const float* __restrict__ lB, const int* __restrict__ obs,
    float* __restrict__ gout) {
  const int n0 = blockIdx.x * SPB;
  const int tid = threadIdx.x;
  const int w = tid >> 6;  // wave 0..7: owns output states [32w, 32w+32)
  const int l = tid & 63;
  const int n = l & 15;    // sequence slot (also A-operand m-slot)
  const int q = l >> 4;    // 0..3

  __shared__ int obs_s[SPB][514];   // 32.9 KB (stride pad for bank spread)
  __shared__ h8 xfrag[2][8][64];    // staged B fragments, 16 KB
  __shared__ float rbuf[SPB][264];  // one output t-row staging, 16.9 KB
  __shared__ float smax[16 * 9 + 8];

  for (int idx = tid; idx < SPB * TT; idx += 512)
    obs_s[idx >> 9][idx & 511] = obs[(size_t)n0 * TT + idx];

  // Static A fragments. Lane map (m89-verified family): m = l&15,
  // k = kc*32 + (l>>4)*8 + e.  fwd: value expA[k][m] (A^T tile, m=state j);
  // bwd: value expA[m][k] (A tile, m=state i).
  h8 afrag[2][8];
#pragma unroll
  for (int mt = 0; mt < 2; ++mt) {
    const int m = (2 * w + mt) * 16 + n;
#pragma unroll
    for (int kc = 0; kc < 8; ++kc) {
#pragma unroll
      for (int e = 0; e < 8; ++e) {
        const int k = kc * 32 + q * 8 + e;
        const float lv = (MODE == 0) ? lA[(size_t)k * KK + m]
                                     : lA[(size_t)m * KK + k];
        afrag[mt][kc][e] = (_Float16)exp2f(lv * LOG2E);
      }
    }
  }

  // Output coords: r = mt*4+reg -> state j = (2w+mt)*16 + q*4 + reg, seq n.
  int jr[8];
#pragma unroll
  for (int r = 0; r < 8; ++r) jr[r] = (2 * w + (r >> 2)) * 16 + q * 4 + (r & 3);
  const float* lbp[8];
#pragma unroll
  for (int r = 0; r < 8; ++r) lbp[r] = lB + (size_t)jr[r] * VV;
  float* gnb = gout + (size_t)(n0 + n) * TT * KK;  // + t*KK + j

  // Fragment-staging target for value (state j, seq n):
  // chunk kc = w, line = 32*mt + 16*(q>>1) + n, elems 4*(q&1)+reg.
  const int lam0 = (q >> 1) * 16 + n;
  const int e0 = (q & 1) * 4;

  __syncthreads();  // obs_s ready

  // Post-dot staging: max-reduce -> B1 -> scale+write xfrag[dst] + rbuf
  // -> B2. un = staged vector values, gv = fp32 output-row values.
  auto stage = [&](const float un[8], const float gv[8], int dst) {
    float m = fmaxf(fmaxf(fmaxf(un[0], un[1]), fmaxf(un[2], un[3])),
                    fmaxf(fmaxf(un[4], un[5]), fmaxf(un[6], un[7])));
    m = fmaxf(m, __shfl_xor(m, 16));
    m = fmaxf(m, __shfl_xor(m, 32));
    if (l < 16) smax[l * 9 + w] = m;
    bar_lds();  // B1
    float mm = smax[n * 9];
#pragma unroll
    for (int ww = 1; ww < 8; ++ww) mm = fmaxf(mm, smax[n * 9 + ww]);
    const float rs = __builtin_amdgcn_rcpf(fmaxf(mm, 1e-30f));
#pragma unroll
    for (int mt = 0; mt < 2; ++mt) {
      h4 hv;
#pragma unroll
      for (int reg = 0; reg < 4; ++reg)
        hv[reg] = (_Float16)(un[mt * 4 + reg] * rs);
      *(h4*)((_Float16*)&xfrag[dst][w][lam0 + 32 * mt] + e0) = hv;
      f4 fv;
#pragma unroll
      for (int reg = 0; reg < 4; ++reg) fv[reg] = gv[mt * 4 + reg];
      *(f4*)&rbuf[n][32 * w + 16 * mt + 4 * q] = fv;  // mt=0 half
      if (mt == 0) continue;  // (kept simple: second write below)
    }
    // note: loop above writes mt=0 slot twice pattern-free; rewrite cleanly:
    bar_lds();  // B2
  };
  (void)stage;  // replaced by inline code below (kept for doc)

  // Flush one gout t-row for all 16 seqs. Wave w: seqs w and w+8.
  auto flush_row = [&](int row) {
    const int l4 = l * 4;
    const f4 v0 = *(const f4*)&rbuf[w][l4];
    const f4 v1 = *(const f4*)&rbuf[w + 8][l4];
    *(f4*)&gout[((size_t)(n0 + w) * TT + row) * KK + l4] = v0;
    *(f4*)&gout[((size_t)(n0 + w + 8) * TT + row) * KK + l4] = v1;
  };

  // Inline staging macro-equivalent (post-B1 writes, explicit and correct).
  auto do_stage = [&](const float un[8], const float gv[8], int dst) {
    float m = fmaxf(fmaxf(fmaxf(un[0], un[1]), fmaxf(un[2], un[3])),
                    fmaxf(fmaxf(un[4], un[5]), fmaxf(un[6], un[7])));
    m = fmaxf(m, __shfl_xor(m, 16));
    m = fmaxf(m, __shfl_xor(m, 32));
    if (l < 16) smax[l * 9 + w] = m;
    bar_lds();  // B1: smax visible; also fences prior flush-reads of rbuf
    float mm = smax[n * 9];
#pragma unroll
    for (int ww = 1; ww < 8; ++ww) mm = fmaxf(mm, smax[n * 9 + ww]);
    const float rs = __builtin_amdgcn_rcpf(fmaxf(mm, 1e-30f));
    h4 h0, h1;
    f4 f0, f1;
#pragma unroll
    for (int reg = 0; reg < 4; ++reg) {
      h0[reg] = (_Float16)(un[reg] * rs);
      h1[reg] = (_Float16)(un[4 + reg] * rs);
      f0[reg] = gv[reg];
      f1[reg] = gv[4 + reg];
    }
    *(h4*)((_Float16*)&xfrag[dst][w][lam0] + e0) = h0;
    *(h4*)((_Float16*)&xfrag[dst][w][lam0 + 32] + e0) = h1;
    *(f4*)&rbuf[n][32 * w + 4 * q] = f0;
    *(f4*)&rbuf[n][32 * w + 16 + 4 * q] = f1;
    bar_lds();  // B2: xfrag + rbuf staged
  };

  if (MODE == 0) {
    // ---- forward ----
    float u[8], bl[8];
    {
      const int o0 = obs_s[n][0];
#pragma unroll
      for (int r = 0; r < 8; ++r)
        u[r] = exp2f((lpi[jr[r]] + lbp[r][o0]) * LOG2E);
    }
    do_stage(u, u, 0);
    flush_row(0);
    {
      const int o1 = obs_s[n][1];
#pragma unroll
      for (int r = 0; r < 8; ++r) bl[r] = lbp[r][o1];
    }

#pragma unroll 1
    for (int t = 0; t < TT - 1; ++t) {
      const int cur = t & 1;
      float bln[8];
      const int o2 = obs_s[n][t + 2 < TT ? t + 2 : 0];
#pragma unroll
      for (int r = 0; r < 8; ++r) bln[r] = lbp[r][o2];
      h8 bfr[8];
#pragma unroll
      for (int kc = 0; kc < 8; ++kc) bfr[kc] = xfrag[cur][kc][l];
      f4 a0a = {0.f, 0.f, 0.f, 0.f}, a0b = a0a, a1a = a0a, a1b = a0a;
#pragma unroll
      for (int kc = 0; kc < 4; ++kc) {
        a0a = __builtin_amdgcn_mfma_f32_16x16x32_f16(afrag[0][kc], bfr[kc],
                                                     a0a, 0, 0, 0);
        a1a = __builtin_amdgcn_mfma_f32_16x16x32_f16(afrag[1][kc], bfr[kc],
                                                     a1a, 0, 0, 0);
      }
#pragma unroll
      for (int kc = 4; kc < 8; ++kc) {
        a0b = __builtin_amdgcn_mfma_f32_16x16x32_f16(afrag[0][kc], bfr[kc],
                                                     a0b, 0, 0, 0);
        a1b = __builtin_amdgcn_mfma_f32_16x16x32_f16(afrag[1][kc], bfr[kc],
                                                     a1b, 0, 0, 0);
      }
      const f4 acc0 = a0a + a0b, acc1 = a1a + a1b;
      float un[8];
#pragma unroll
      for (int r = 0; r < 8; ++r) {
        const float D = (r < 4) ? acc0[r] : acc1[r - 4];
        un[r] = D * exp2f(bl[r] * LOG2E);  // scaled alpha_{t+1}
      }
      do_stage(un, un, cur ^ 1);  // B1 + writes + B2 inside
      flush_row(t + 1);
#pragma unroll
      for (int r = 0; r < 8; ++r) bl[r] = bln[r];
    }
  } else {
    // ---- backward + fused gamma ----
    float u[8], bl[8], ap[8];
    {
      const int oL = obs_s[n][TT - 1];
#pragma unroll
      for (int r = 0; r < 8; ++r) u[r] = exp2f(lbp[r][oL] * LOG2E);  // w_511
    }
    do_stage(u, u, 0);  // rbuf content unused (no flush here)
    {
      const int oP = obs_s[n][TT - 2];
#pragma unroll
      for (int r = 0; r < 8; ++r) bl[r] = lbp[r][oP];
#pragma unroll
      for (int r = 0; r < 8; ++r) ap[r] = gnb[(size_t)(TT - 2) * KK + jr[r]];
    }

#pragma unroll 1
    for (int t = TT - 2; t >= 0; --t) {
      const int cur = (TT - 2 - t) & 1;
      float apn[8], bln[8];
      const int tp = t > 0 ? t - 1 : 0;
      const int o2 = obs_s[n][tp];
#pragma unroll
      for (int r = 0; r < 8; ++r) bln[r] = lbp[r][o2];
#pragma unroll
      for (int r = 0; r < 8; ++r) apn[r] = gnb[(size_t)tp * KK + jr[r]];
      h8 bfr[8];
#pragma unroll
      for (int kc = 0; kc < 8; ++kc) bfr[kc] = xfrag[cur][kc][l];
      f4 a0a = {0.f, 0.f, 0.f, 0.f}, a0b = a0a, a1a = a0a, a1b = a0a;
#pragma unroll
      for (int kc = 0; kc < 4; ++kc) {
        a0a = __builtin_amdgcn_mfma_f32_16x16x32_f16(afrag[0][kc], bfr[kc],
                                                     a0a, 0, 0, 0);
        a1a = __builtin_amdgcn_mfma_f32_16x16x32_f16(afrag[1][kc], bfr[kc],
                                                     a1a, 0, 0, 0);
      }
#pragma unroll
      for (int kc = 4; kc < 8; ++kc) {
        a0b = __builtin_amdgcn_mfma_f32_16x16x32_f16(afrag[0][kc], bfr[kc],
                                                     a0b, 0, 0, 0);
        a1b = __builtin_amdgcn_mfma_f32_16x16x32_f16(afrag[1][kc], bfr[kc],
                                                     a1b, 0, 0, 0);
      }
      const f4 acc0 = a0a + a0b, acc1 = a1a + a1b;
      float un[8], gv[8];
#pragma unroll
      for (int r = 0; r < 8; ++r) {
        const float beta = (r < 4) ? acc0[r] : acc1[r - 4];  // scaled beta_t
        gv[r] = ap[r] * beta;                 // gamma numerator row t (fp32)
        un[r] = beta * exp2f(bl[r] * LOG2E);  // w_t
      }
      do_stage(un, gv, cur ^ 1);  // B1 + writes + B2 inside
      flush_row(t);               // overwrite gout row t
#pragma unroll
      for (int r = 0; r < 8; ++r) { ap[r] = apn[r]; bl[r] = bln[r]; }
    }
  }
}

// Pass 3: log-normalize each (n,t) row of 256 positive scaled alpha*beta
// values in place: out = (log2(v) - log2(sum v)) * ln2. Pure streaming.
__global__ __launch_bounds__(256) void gamma_norm(float* __restrict__ gout) {
  const int wave = blockIdx.x * 4 + (threadIdx.x >> 6);
  const int c = threadIdx.x & 63;
  const int stride = gridDim.x * 4;
#pragma unroll 1
  for (int row = wave; row < NB * TT; row += stride) {
    float* p = gout + (size_t)row * KK + c * 4;
    const f4 v = *(const f4*)p;
    float s = (v[0] + v[1]) + (v[2] + v[3]);
#pragma unroll
    for (int d = 1; d < 64; d <<= 1) s += __shfl_xor(s, d);
    const float lg = __log2f(s);
    f4 o;
    o[0] = (__log2f(v[0]) - lg) * LN2;
    o[1] = (__log2f(v[1]) - lg) * LN2;
    o[2] = (__log2f(v[2]) - lg) * LN2;
    o[3] = (__log2f(v[3]) - lg) * LN2;
    *(f4*)p = o;
  }
}

extern "C" void kernel_launch(void* const* d_in, const int* in_sizes, int n_in,
                              void* d_out, int out_size, void* d_ws, size_t ws_size,
                              hipStream_t stream) {
  const float* lpi = (const float*)d_in[0];
  const float* lA = (const float*)d_in[1];
  const float* lB = (const float*)d_in[2];
  const int* obs = (const int*)d_in[3];
  float* gout = (float*)d_out;
  (void)d_ws; (void)ws_size;  // deliberately unused

  hmm_mfma<0><<<NBLK, 512, 0, stream>>>(lpi, lA, lB, obs, gout);
  hmm_mfma<1><<<NBLK, 512, 0, stream>>>(lpi, lA, lB, obs, gout);
  gamma_norm<<<2048, 256, 0, stream>>>(gout);
}

// Round 7
// 679.941 us; speedup vs baseline: 6.4596x; 6.4596x over previous
//
#include <hip/hip_runtime.h>
#include <stdint.h>

// Baum-Welch forward-backward posteriors (log_gamma), MI355X gfx950.
//
// R10 -> R11: kill the emission-gather stall; overlap fwd and bwd.
//  - R10 counters: 10.5K cy/step, 85% stall, FETCH 224MB. Cause: 4096
//    single-dword emission gathers/step/block over 4096 distinct 64B lines
//    (16KB stride) -> L1-miss storm serialized through one CU's L2 port.
//  - Fix 1: pre-pass writes ebT[v][k] = exp(lB[k][v]) (4MB in d_ws).
//    Emission access becomes 2 x dwordx4 per lane from a 16KB L1-resident
//    row set; also deletes 8 exp2f/lane/step. bwd alpha reads: same shape.
//  - Fix 2: fwd and bwd run CONCURRENTLY (32 blocks, one kernel): bwd
//    stores raw scaled beta to d_ws; gamma = alpha*beta + log-normalize
//    in a streaming pass (402MB, ~75us). Host gates on ws_size with
//    sequential fallbacks (fused-gamma bwd), so correctness never depends
//    on workspace size.
//  - MFMA recurrence structure, fragment-staging math, do_stage barrier
//    discipline (reduce -> B1 -> writes -> B2 -> flush) byte-identical to
//    R10 (which passed).

#define NB 256
#define TT 512
#define KK 256
#define VV 4096
#define SPB 16            // sequences per block
#define NBLK (NB / SPB)   // 16 recurrence blocks per direction
#define LOG2E 1.44269504088896f
#define LN2 0.693147180559945f

typedef float f4 __attribute__((ext_vector_type(4)));
typedef _Float16 h8 __attribute__((ext_vector_type(8)));
typedef _Float16 h4 __attribute__((ext_vector_type(4)));

struct SmemT {
  int obs_s[SPB][514];   // 32.9 KB
  h8 xfrag[2][8][64];    // 16 KB  staged B fragments
  float rbuf[SPB][264];  // 16.9 KB one output t-row staging
  float smax[16 * 9 + 8];
};

__device__ __forceinline__ void bar_lds() {
  asm volatile("s_waitcnt lgkmcnt(0)" ::: "memory");
  __builtin_amdgcn_s_barrier();
}

// MODE 0: forward, writes scaled fp32 alpha rows to outp (=gout).
// MODE 1: backward fused-gamma (sequential tier): reads alpha rows from
//         gout, overwrites rows 510..0 with alpha*beta (row 511 stays alpha).
// MODE 2: backward to workspace (concurrent tier): writes raw scaled beta
//         rows 0..511 to outp (=wsbeta), row 511 = 1.
template <int MODE, bool TRANS>
__device__ __forceinline__ void hmm_body(
    SmemT& sm, int blk, const float* __restrict__ lpi,
    const float* __restrict__ lA, const float* __restrict__ lB,
    const float* __restrict__ ebT, const int* __restrict__ obs,
    float* __restrict__ gout, float* __restrict__ outp) {
  const int n0 = blk * SPB;
  const int tid = threadIdx.x;
  const int w = tid >> 6;  // wave 0..7: owns output states [32w, 32w+32)
  const int l = tid & 63;
  const int n = l & 15;    // sequence slot (also A-operand m-slot)
  const int q = l >> 4;    // 0..3
  const int j0 = 32 * w + 4 * q;  // lane's output states: j0..j0+3, +16..+19

  for (int idx = tid; idx < SPB * TT; idx += 512)
    sm.obs_s[idx >> 9][idx & 511] = obs[(size_t)n0 * TT + idx];

  // Static A fragments (m89-verified map): m = l&15, k = kc*32 + q*8 + e.
  // fwd: expA[k][m] (A^T tile, m = state j); bwd: expA[m][k] (A tile).
  h8 afrag[2][8];
#pragma unroll
  for (int mt = 0; mt < 2; ++mt) {
    const int m = (2 * w + mt) * 16 + n;
#pragma unroll
    for (int kc = 0; kc < 8; ++kc) {
#pragma unroll
      for (int e = 0; e < 8; ++e) {
        const int k = kc * 32 + q * 8 + e;
        const float lv = (MODE == 0) ? lA[(size_t)k * KK + m]
                                     : lA[(size_t)m * KK + k];
        afrag[mt][kc][e] = (_Float16)exp2f(lv * LOG2E);
      }
    }
  }

  // Fragment-staging target for value (state j, seq n): chunk kc = w,
  // line 32*mt + 16*(q>>1) + n, elems 4*(q&1)+reg. (R10-verified.)
  const int lam0 = (q >> 1) * 16 + n;
  const int e0 = (q & 1) * 4;

  __syncthreads();  // obs_s ready

  // Emission factors for time te, lane's 8 states (TRANS: already exp'd).
  auto emis = [&](int te, f4& ea, f4& eb) {
    const int o = sm.obs_s[n][te];
    if constexpr (TRANS) {
      const float* er = ebT + (size_t)o * KK + j0;
      ea = *(const f4*)er;
      eb = *(const f4*)(er + 16);
    } else {
#pragma unroll
      for (int r = 0; r < 4; ++r) {
        ea[r] = lB[(size_t)(j0 + r) * VV + o];
        eb[r] = lB[(size_t)(j0 + 16 + r) * VV + o];
      }
    }
  };
  auto efac = [&](const f4& ea, const f4& eb, int r) -> float {
    const float v = (r < 4) ? ea[r] : eb[r - 4];
    if constexpr (TRANS) return v;
    return exp2f(v * LOG2E);
  };

  // reduce -> B1 -> scale+write xfrag[dst] + rbuf -> B2.  (R10-identical.)
  auto do_stage = [&](const float un[8], const float gv[8], int dst) {
    float m = fmaxf(fmaxf(fmaxf(un[0], un[1]), fmaxf(un[2], un[3])),
                    fmaxf(fmaxf(un[4], un[5]), fmaxf(un[6], un[7])));
    m = fmaxf(m, __shfl_xor(m, 16));
    m = fmaxf(m, __shfl_xor(m, 32));
    if (l < 16) sm.smax[l * 9 + w] = m;
    bar_lds();  // B1: smax visible; fences prior flush-reads of rbuf
    float mm = sm.smax[n * 9];
#pragma unroll
    for (int ww = 1; ww < 8; ++ww) mm = fmaxf(mm, sm.smax[n * 9 + ww]);
    const float rs = __builtin_amdgcn_rcpf(fmaxf(mm, 1e-30f));
    h4 h0, h1;
    f4 f0, f1;
#pragma unroll
    for (int reg = 0; reg < 4; ++reg) {
      h0[reg] = (_Float16)(un[reg] * rs);
      h1[reg] = (_Float16)(un[4 + reg] * rs);
      f0[reg] = gv[reg];
      f1[reg] = gv[4 + reg];
    }
    *(h4*)((_Float16*)&sm.xfrag[dst][w][lam0] + e0) = h0;
    *(h4*)((_Float16*)&sm.xfrag[dst][w][lam0 + 32] + e0) = h1;
    *(f4*)&sm.rbuf[n][32 * w + 4 * q] = f0;
    *(f4*)&sm.rbuf[n][32 * w + 16 + 4 * q] = f1;
    bar_lds();  // B2: xfrag + rbuf staged
  };

  // Flush one t-row for all 16 seqs. Wave w: seqs w and w+8.
  auto flush_row = [&](int row) {
    const int l4 = l * 4;
    const f4 v0 = *(const f4*)&sm.rbuf[w][l4];
    const f4 v1 = *(const f4*)&sm.rbuf[w + 8][l4];
    *(f4*)&outp[((size_t)(n0 + w) * TT + row) * KK + l4] = v0;
    *(f4*)&outp[((size_t)(n0 + w + 8) * TT + row) * KK + l4] = v1;
  };

  // One recurrence step: acc = A-tiles x staged fragments.
  auto mfma_step = [&](int cur, f4& acc0, f4& acc1) {
    h8 bfr[8];
#pragma unroll
    for (int kc = 0; kc < 8; ++kc) bfr[kc] = sm.xfrag[cur][kc][l];
    f4 a0a = {0.f, 0.f, 0.f, 0.f}, a0b = a0a, a1a = a0a, a1b = a0a;
#pragma unroll
    for (int kc = 0; kc < 4; ++kc) {
      a0a = __builtin_amdgcn_mfma_f32_16x16x32_f16(afrag[0][kc], bfr[kc],
                                                   a0a, 0, 0, 0);
      a1a = __builtin_amdgcn_mfma_f32_16x16x32_f16(afrag[1][kc], bfr[kc],
                                                   a1a, 0, 0, 0);
    }
#pragma unroll
    for (int kc = 4; kc < 8; ++kc) {
      a0b = __builtin_amdgcn_mfma_f32_16x16x32_f16(afrag[0][kc], bfr[kc],
                                                   a0b, 0, 0, 0);
      a1b = __builtin_amdgcn_mfma_f32_16x16x32_f16(afrag[1][kc], bfr[kc],
                                                   a1b, 0, 0, 0);
    }
    acc0 = a0a + a0b;
    acc1 = a1a + a1b;
  };

  if (MODE == 0) {
    // ---- forward ----
    f4 eca, ecb;
    emis(0, eca, ecb);
    float u[8];
#pragma unroll
    for (int r = 0; r < 8; ++r) {
      const int jr = j0 + 16 * (r >> 2) + (r & 3);
      u[r] = exp2f(lpi[jr] * LOG2E) * efac(eca, ecb, r);
    }
    do_stage(u, u, 0);
    flush_row(0);
    emis(1, eca, ecb);

#pragma unroll 1
    for (int t = 0; t < TT - 1; ++t) {
      f4 pa, pb;
      emis(t + 2 < TT ? t + 2 : 0, pa, pb);  // prefetch o_{t+2}
      f4 acc0, acc1;
      mfma_step(t & 1, acc0, acc1);
      float un[8];
#pragma unroll
      for (int r = 0; r < 8; ++r) {
        const float D = (r < 4) ? acc0[r] : acc1[r - 4];
        un[r] = D * efac(eca, ecb, r);  // scaled alpha_{t+1}
      }
      do_stage(un, un, (t & 1) ^ 1);
      flush_row(t + 1);
      eca = pa;
      ecb = pb;
    }
  } else {
    // ---- backward (MODE1: fused gamma to gout; MODE2: raw beta to ws) ----
    f4 eca, ecb;
    emis(TT - 1, eca, ecb);
    float u[8], ones[8];
#pragma unroll
    for (int r = 0; r < 8; ++r) {
      u[r] = efac(eca, ecb, r);  // w_511
      ones[r] = 1.0f;
    }
    do_stage(u, ones, 0);
    if (MODE == 2) flush_row(TT - 1);  // beta row 511 = 1
    emis(TT - 2, eca, ecb);
    f4 aa = {0.f, 0.f, 0.f, 0.f}, ab = aa;
    if (MODE == 1) {
      const float* ar = gout + ((size_t)(n0 + n) * TT + (TT - 2)) * KK + j0;
      aa = *(const f4*)ar;
      ab = *(const f4*)(ar + 16);
    }

#pragma unroll 1
    for (int t = TT - 2; t >= 0; --t) {
      const int tp = t > 0 ? t - 1 : 0;
      f4 pa, pb;
      emis(tp, pa, pb);  // prefetch o_{t-1}
      f4 naa = {0.f, 0.f, 0.f, 0.f}, nab = naa;
      if (MODE == 1) {
        const float* ar = gout + ((size_t)(n0 + n) * TT + tp) * KK + j0;
        naa = *(const f4*)ar;
        nab = *(const f4*)(ar + 16);
      }
      f4 acc0, acc1;
      mfma_step((TT - 2 - t) & 1, acc0, acc1);
      float un[8], gv[8];
#pragma unroll
      for (int r = 0; r < 8; ++r) {
        const float beta = (r < 4) ? acc0[r] : acc1[r - 4];  // scaled beta_t
        const float ap = (r < 4) ? aa[r] : ab[r - 4];
        gv[r] = (MODE == 1) ? ap * beta : beta;
        un[r] = beta * efac(eca, ecb, r);  // w_t
      }
      do_stage(un, gv, ((TT - 2 - t) & 1) ^ 1);
      flush_row(t);
      eca = pa;
      ecb = pb;
      aa = naa;
      ab = nab;
    }
  }
}

// Concurrent tier: blocks [0,16) forward -> gout, [16,32) backward -> wsbeta.
template <bool TRANS>
__global__ __launch_bounds__(512, 1) void hmm_combined(
    const float* __restrict__ lpi, const float* __restrict__ lA,
    const float* __restrict__ lB, const float* __restrict__ ebT,
    const int* __restrict__ obs, float* __restrict__ gout,
    float* __restrict__ wsbeta) {
  __shared__ SmemT sm;
  if (blockIdx.x < NBLK)
    hmm_body<0, TRANS>(sm, blockIdx.x, lpi, lA, lB, ebT, obs, gout, gout);
  else
    hmm_body<2, TRANS>(sm, blockIdx.x - NBLK, lpi, lA, lB, ebT, obs, gout,
                       wsbeta);
}

// Sequential tier.
template <int MODE, bool TRANS>
__global__ __launch_bounds__(512, 1) void hmm_one(
    const float* __restrict__ lpi, const float* __restrict__ lA,
    const float* __restrict__ lB, const float* __restrict__ ebT,
    const int* __restrict__ obs, float* __restrict__ gout) {
  __shared__ SmemT sm;
  hmm_body<MODE, TRANS>(sm, blockIdx.x, lpi, lA, lB, ebT, obs, gout, gout);
}

// ebT[v][k] = exp(lB[k][v]). 4MB; reads are L2-hot after warm.
__global__ __launch_bounds__(256) void expT(const float* __restrict__ lB,
                                            float* __restrict__ ebT) {
#pragma unroll 1
  for (int v = blockIdx.x; v < VV; v += gridDim.x)
    for (int k = threadIdx.x; k < KK; k += 256)
      ebT[(size_t)v * KK + k] = exp2f(lB[(size_t)k * VV + v] * LOG2E);
}

// Concurrent tier pass 3: gamma = alpha (gout) * beta (ws), log-normalized.
__global__ __launch_bounds__(256) void gamma_mul_norm(
    float* __restrict__ gout, const float* __restrict__ beta) {
  const int wave = blockIdx.x * 4 + (threadIdx.x >> 6);
  const int c = threadIdx.x & 63;
  const int stride = gridDim.x * 4;
#pragma unroll 1
  for (int row = wave; row < NB * TT; row += stride) {
    float* p = gout + (size_t)row * KK + c * 4;
    const f4 a = *(const f4*)p;
    const f4 b = *(const f4*)(beta + (size_t)row * KK + c * 4);
    const f4 v = a * b;
    float s = (v[0] + v[1]) + (v[2] + v[3]);
#pragma unroll
    for (int d = 1; d < 64; d <<= 1) s += __shfl_xor(s, d);
    const float lg = __log2f(s);
    f4 o;
    o[0] = (__log2f(v[0]) - lg) * LN2;
    o[1] = (__log2f(v[1]) - lg) * LN2;
    o[2] = (__log2f(v[2]) - lg) * LN2;
    o[3] = (__log2f(v[3]) - lg) * LN2;
    *(f4*)p = o;
  }
}

// Sequential tier pass 3: rows already hold alpha*beta; log-normalize.
__global__ __launch_bounds__(256) void gamma_norm(float* __restrict__ gout) {
  const int wave = blockIdx.x * 4 + (threadIdx.x >> 6);
  const int c = threadIdx.x & 63;
  const int stride = gridDim.x * 4;
#pragma unroll 1
  for (int row = wave; row < NB * TT; row += stride) {
    float* p = gout + (size_t)row * KK + c * 4;
    const f4 v = *(const f4*)p;
    float s = (v[0] + v[1]) + (v[2] + v[3]);
#pragma unroll
    for (int d = 1; d < 64; d <<= 1) s += __shfl_xor(s, d);
    const float lg = __log2f(s);
    f4 o;
    o[0] = (__log2f(v[0]) - lg) * LN2;
    o[1] = (__log2f(v[1]) - lg) * LN2;
    o[2] = (__log2f(v[2]) - lg) * LN2;
    o[3] = (__log2f(v[3]) - lg) * LN2;
    *(f4*)p = o;
  }
}

extern "C" void kernel_launch(void* const* d_in, const int* in_sizes, int n_in,
                              void* d_out, int out_size, void* d_ws, size_t ws_size,
                              hipStream_t stream) {
  const float* lpi = (const float*)d_in[0];
  const float* lA = (const float*)d_in[1];
  const float* lB = (const float*)d_in[2];
  const int* obs = (const int*)d_in[3];
  float* gout = (float*)d_out;

  const size_t EBT_B = (size_t)VV * KK * sizeof(float);        // 4 MB
  const size_t BETA_B = (size_t)NB * TT * KK * sizeof(float);  // 134 MB
  float* ebT = (float*)d_ws;
  float* wsbeta = (float*)((char*)d_ws + EBT_B);

  if (ws_size >= EBT_B + BETA_B) {
    expT<<<2048, 256, 0, stream>>>(lB, ebT);
    hmm_combined<true><<<2 * NBLK, 512, 0, stream>>>(lpi, lA, lB, ebT, obs,
                                                     gout, wsbeta);
    gamma_mul_norm<<<2048, 256, 0, stream>>>(gout, wsbeta);
  } else if (ws_size >= EBT_B) {
    expT<<<2048, 256, 0, stream>>>(lB, ebT);
    hmm_one<0, true><<<NBLK, 512, 0, stream>>>(lpi, lA, lB, ebT, obs, gout);
    hmm_one<1, true><<<NBLK, 512, 0, stream>>>(lpi, lA, lB, ebT, obs, gout);
    gamma_norm<<<2048, 256, 0, stream>>>(gout);
  } else {
    hmm_one<0, false><<<NBLK, 512, 0, stream>>>(lpi, lA, lB, nullptr, obs, gout);
    hmm_one<1, false><<<NBLK, 512, 0, stream>>>(lpi, lA, lB, nullptr, obs, gout);
    gamma_norm<<<2048, 256, 0, stream>>>(gout);
  }
}